// Round 7
// baseline (119.994 us; speedup 1.0000x reference)
//
#include <hip/hip_runtime.h>
#include <hip/hip_bf16.h>

#define F_IN   64
#define NN     24
#define HH     64
#define CC     1536           // Wh columns
#define CCX    1584           // + 48 f1/f2 columns
#define NTILE  99             // 1584 / 16 MFMA column tiles
#define ROWS   16             // BT rows per group (M=16 MFMA fully used)
#define GRPS   8              // row-groups per block
#define BT_TOT (16 * 2048)    // 32768
#define ALPHA_ 0.2f
#define NEG_INF_ -9.0e15f
#define LOG2E_ 1.4426950408889634f
#define XSP    72             // xs16 row stride in shorts (144 B)
#define ATS    24             // attn16 row stride in shorts (48 B, 16B-aligned)

typedef short bf16x8 __attribute__((ext_vector_type(8)));
typedef float f32x4  __attribute__((ext_vector_type(4)));

#if defined(__has_builtin)
#  if __has_builtin(__builtin_amdgcn_cvt_pk_bf16_f32)
#    define HAS_PK_BF16 1
#  endif
#  if __has_builtin(__builtin_amdgcn_exp2f)
#    define HAS_EXP2 1
#  endif
#  if __has_builtin(__builtin_amdgcn_rcpf)
#    define HAS_RCP 1
#  endif
#  if __has_builtin(__builtin_amdgcn_fmed3f)
#    define HAS_MED3 1
#  endif
#endif
#ifndef HAS_PK_BF16
#  define HAS_PK_BF16 0
#endif
#ifndef HAS_EXP2
#  define HAS_EXP2 0
#endif
#ifndef HAS_RCP
#  define HAS_RCP 0
#endif
#ifndef HAS_MED3
#  define HAS_MED3 0
#endif

// fp32 -> bf16 bits, round-to-nearest-even
__device__ __forceinline__ short f2bf(float f) {
    unsigned u = __float_as_uint(f);
    return (short)((u + 0x7FFFu + ((u >> 16) & 1u)) >> 16);
}

// two fp32 -> packed bf16 pair in one int (low = a, high = b)
__device__ __forceinline__ int pk2bf(float a, float b) {
#if HAS_PK_BF16
    typedef __bf16 bfv2 __attribute__((ext_vector_type(2)));
    bfv2 r = __builtin_amdgcn_cvt_pk_bf16_f32(a, b);
    return __builtin_bit_cast(int, r);
#else
    return (int)(unsigned short)f2bf(a) | ((int)f2bf(b) << 16);
#endif
}

// 2^x, single v_exp_f32
__device__ __forceinline__ float exp2_fast(float x) {
#if HAS_EXP2
    return __builtin_amdgcn_exp2f(x);
#else
    return __expf(0.6931471805599453f * x);
#endif
}

// fast reciprocal (v_rcp_f32); ~1e-7 rel err, fine for bf16 attention weights
__device__ __forceinline__ float rcp_fast(float x) {
#if HAS_RCP
    return __builtin_amdgcn_rcpf(x);
#else
    return 1.0f / x;
#endif
}

// ELU(v) = median(v, e^v - 1, 0): v>0 -> med=v; v<=0 -> med=e^v-1. Inf-safe.
__device__ __forceinline__ float elu_fast(float v) {
#if HAS_MED3
    return __builtin_amdgcn_fmed3f(v, exp2_fast(v * LOG2E_) - 1.f, 0.f);
#else
    return (v > 0.f) ? v : (exp2_fast(v * LOG2E_) - 1.f);
#endif
}

// ---------------------------------------------------------------------------
// Precompute: unchanged from r4 (verified).
// ---------------------------------------------------------------------------
__global__ __launch_bounds__(256) void precompute_kernel(
    const float* __restrict__ Wp,
    const float* __restrict__ bp,
    const float* __restrict__ W,
    const float* __restrict__ a,
    const int*   __restrict__ adj,
    short* __restrict__ Bpk,
    float* __restrict__ bpWx,
    float* __restrict__ maskf)
{
    __shared__ float WpS[64 * 65];
    __shared__ float WS[64 * 17];
    __shared__ float Wa[128];
    const int b = blockIdx.x, tid = threadIdx.x;

    if (b < 96) {
        const int n64 = (b >> 2) * 64;
        const int jc0 = (b & 3) * 16;
        for (int i = tid; i < 4096; i += 256)
            WpS[(i >> 6) * 65 + (i & 63)] = Wp[(size_t)(i >> 6) * CC + n64 + (i & 63)];
        for (int i = tid; i < 1024; i += 256)
            WS[(i >> 4) * 17 + (i & 15)] = W[(i >> 4) * 64 + jc0 + (i & 15)];
        __syncthreads();

        const int k = tid & 63, q0 = (tid >> 6) * 4;
        float acc[4] = {0.f, 0.f, 0.f, 0.f};
        #pragma unroll 4
        for (int m = 0; m < 64; ++m) {
            const float wp = WpS[k * 65 + m];
            #pragma unroll
            for (int j = 0; j < 4; ++j)
                acc[j] += wp * WS[m * 17 + q0 + j];
        }
        const int s2 = k >> 5, jj = k & 7, lbase = ((k >> 3) & 3) * 16;
        #pragma unroll
        for (int j = 0; j < 4; ++j) {
            const int l = lbase + q0 + j;
            Bpk[((size_t)(b * 2 + s2) * 64 + l) * 8 + jj] = f2bf(acc[j]);
        }
    } else {
        const bool needWa = (b < 108) || (b == 114);
        if (needWa) {
            if (tid < 128) {
                const int which = tid >> 6, m = tid & 63;
                float s = 0.f;
                #pragma unroll 8
                for (int h = 0; h < 64; ++h)
                    s += W[m * 64 + h] * a[which * 64 + h];
                Wa[tid] = s;
            }
            __syncthreads();
        }
        if (b < 108) {
            const int u  = (b - 96) * 256 + tid;
            const int jj = u & 7, l = (u >> 3) & 63, s2 = (u >> 9) & 1, te = u >> 10;
            const int t  = 96 + te;
            const int k  = s2 * 32 + ((l >> 4) << 3) + jj;
            const int ff = te * 16 + (l & 15);
            const int which = (ff >= NN) ? 1 : 0;
            const int node  = ff - which * NN;
            float v = 0.f;
            #pragma unroll 8
            for (int m = 0; m < 64; ++m)
                v += Wp[(size_t)k * CC + node * 64 + m] * Wa[which * 64 + m];
            Bpk[((size_t)(t * 2 + s2) * 64 + l) * 8 + jj] = f2bf(v * LOG2E_);
        } else {
            const int c = (b - 108) * 256 + tid;
            if (c < CC) {
                const int n = c >> 6, jc = c & 63;
                float s = 0.f;
                #pragma unroll 8
                for (int m = 0; m < 64; ++m) s += bp[n * 64 + m] * W[m * 64 + jc];
                bpWx[c] = s;
            } else if (c < CCX) {
                const int ff = c - CC;
                const int which = (ff >= NN) ? 1 : 0;
                const int node  = ff - which * NN;
                float s = 0.f;
                #pragma unroll 8
                for (int m = 0; m < 64; ++m) s += bp[node * 64 + m] * Wa[which * 64 + m];
                bpWx[c] = s * LOG2E_;
            }
            if (b == 114) {                  // additive mask: 0 or NEG_INF
                for (int i = tid; i < NN * NN; i += 256)
                    maskf[i] = (adj[i] > 0) ? 0.f : NEG_INF_;
            }
        }
    }
}

// ---------------------------------------------------------------------------
// Main fused kernel, v7 (= v6 + streamed-tile stride fix):
// 256 blocks x 1024 threads, 1 block/CU, each block iterates GRPS=8
// row-groups of 16 BT rows.
//   Weight residency: waves 0..11 hold B-tiles k=0..3 (+biases) in VGPRs for
//   the whole kernel (loaded once); tiles k=4..7 are streamed per group from
//   L2 with loop-invariant addresses. f-waves (12..14) hold their single tile
//   fully resident. x for group it+1 is prefetched at phase-2 start of it.
//   3 barriers per group: xs-write -> B1 -> P2 -> B2 -> P3 -> B3.
// ---------------------------------------------------------------------------
__global__ __launch_bounds__(1024, 4) void gat_main_kernel(
    const float* __restrict__ x,
    const float* __restrict__ maskf,
    const short* __restrict__ Bpk,
    const float* __restrict__ bpWx,
    float* __restrict__ out)
{
    __shared__ __align__(16) short xs16[ROWS * XSP];          //  2304 B
    __shared__ __align__(16) short whB[ROWS * 4 * 48 * 8];    // 49152 B (PV B-frags)
    __shared__ __align__(16) short attn16[ROWS * NN * ATS];   // 18432 B (PV A, 24x24)
    __shared__ __align__(16) short zero16[8];                 //    16 B (zero bcast)
    __shared__ __align__(16) float maskQ[6 * 24 * 4];         //  2304 B (mask, q-transposed)
    __shared__ float fs[ROWS * 48];                           //  3072 B (f1|f2)

    const int tid  = threadIdx.x;
    const int lane = tid & 63;
    const int wid  = tid >> 6;           // 0..15
    const int quad = lane >> 4;
    const int lm   = lane & 15;

    const int g  = wid >> 2;             // valid for wid<12
    const int nt = wid & 3;

    // ---- one-time staging: zero frag + transposed mask ----
    if (tid < 8) zero16[tid] = 0;
    if (tid < NN * NN) {
        const int i = tid / NN, rem = tid - i * NN;
        const int gg = (rem >= 12) ? 1 : 0;
        const int jl = rem - gg * 12;
        const int q = jl >> 2, c = jl & 3;
        maskQ[((gg * 3 + q) * NN + i) * 4 + c] = maskf[tid];
    }

    // ---- one-time load of resident weights (live whole kernel) ----
    bf16x8 rb0[4], rb1[4];               // waves 0..11: tiles k=0..3
    float  rbias[4];                     // waves 12..14: tile in rb0[0]/rb1[0]
    if (wid < 12) {
        #pragma unroll
        for (int k = 0; k < 4; ++k) {
            const int t = (g * 8 + k) * 4 + nt;
            const short* bq = Bpk + ((size_t)(t * 2) * 64 + lane) * 8;
            rb0[k] = *(const bf16x8*)bq;
            rb1[k] = *(const bf16x8*)(bq + 512);
            rbias[k] = bpWx[t * 16 + lm];
        }
    } else if (wid < 15) {
        const int t = 96 + (wid - 12);
        const short* bq = Bpk + ((size_t)(t * 2) * 64 + lane) * 8;
        rb0[0] = *(const bf16x8*)bq;
        rb1[0] = *(const bf16x8*)(bq + 512);
        rbias[0] = bpWx[t * 16 + lm];
    }

    // streamed-tile base pointer (loop-invariant address, k=4..7)
    const short* sbq = (wid < 12)
        ? (Bpk + ((size_t)(((g * 8 + 4) * 4 + nt) * 2) * 64 + lane) * 8)
        : Bpk;                            // dummy (unused)
    const float* sbias = (wid < 12) ? (bpWx + ((g * 8 + 4) * 4 + nt) * 16 + lm)
                                    : bpWx;

    // x prefetch for group 0
    const size_t xstep = (size_t)ROWS * F_IN;       // 1024
    size_t xoff = (size_t)blockIdx.x * GRPS * xstep + tid;
    float xval = x[xoff];

    #pragma unroll 1
    for (int it = 0; it < GRPS; ++it) {
        const size_t base = (size_t)(blockIdx.x * GRPS + it) * ROWS;

        // stage x rows as bf16 (A-operand): 1 elem/thread
        {
            const int rr = tid >> 6, k = tid & 63;
            xs16[rr * XSP + k] = f2bf(xval);
        }
        __syncthreads();                               // B1

        // prefetch next group's x (hidden under P2+P3)
        if (it + 1 < GRPS) {
            xoff += xstep;
            xval = x[xoff];
        }

        // ---------- Phase 2 (MFMA): [Wh | f1 | f2] ----------
        {
            const bf16x8 a0 = *(const bf16x8*)(xs16 + lm * XSP + quad * 8);
            const bf16x8 a1 = *(const bf16x8*)(xs16 + lm * XSP + 32 + quad * 8);

            if (wid < 12) {
                short* wb0 = whB + ((nt * 48 + g * 16 + lm) * 8) + quad * 4 * 1536;
                int pA[4], pB[4];
                {   // ---- half 0: resident tiles k=0..3 (jj 0..3) ----
                    f32x4 acc[4];
                    #pragma unroll
                    for (int k = 0; k < 4; ++k) {
                        f32x4 c = {rbias[k], rbias[k], rbias[k], rbias[k]};
                        c = __builtin_amdgcn_mfma_f32_16x16x32_bf16(a0, rb0[k], c, 0, 0, 0);
                        c = __builtin_amdgcn_mfma_f32_16x16x32_bf16(a1, rb1[k], c, 0, 0, 0);
                        acc[k] = c;
                    }
                    #pragma unroll
                    for (int i = 0; i < 4; ++i) {
                        pA[i] = pk2bf(acc[0][i], acc[1][i]);
                        pB[i] = pk2bf(acc[2][i], acc[3][i]);
                    }
                }
                {   // ---- half 1: streamed tiles k=4..7 (jj 4..7) ----
                    f32x4 acc[4];
                    #pragma unroll
                    for (int k = 0; k < 4; ++k) {
                        // consecutive k at fixed nt are 4 tiles apart;
                        // one tile = 2*64*8 = 1024 shorts -> stride 4096.
                        const short* bq = sbq + (size_t)k * 4 * 1024;
                        const bf16x8 b0 = *(const bf16x8*)bq;
                        const bf16x8 b1 = *(const bf16x8*)(bq + 512);
                        const float bb = sbias[k * 64];
                        f32x4 c = {bb, bb, bb, bb};
                        c = __builtin_amdgcn_mfma_f32_16x16x32_bf16(a0, b0, c, 0, 0, 0);
                        c = __builtin_amdgcn_mfma_f32_16x16x32_bf16(a1, b1, c, 0, 0, 0);
                        acc[k] = c;
                    }
                    #pragma unroll
                    for (int i = 0; i < 4; ++i) {
                        int4 w;
                        w.x = pA[i];
                        w.y = pB[i];
                        w.z = pk2bf(acc[0][i], acc[1][i]);
                        w.w = pk2bf(acc[2][i], acc[3][i]);
                        *(int4*)(wb0 + i * 1536) = w;   // conflict-free (bank floor)
                    }
                }
            } else if (wid < 15) {
                // f1/f2 tiles 96..98 (fully resident)
                const int t = 96 + (wid - 12);
                const float bb = rbias[0];
                f32x4 acc = {bb, bb, bb, bb};
                acc = __builtin_amdgcn_mfma_f32_16x16x32_bf16(a0, rb0[0], acc, 0, 0, 0);
                acc = __builtin_amdgcn_mfma_f32_16x16x32_bf16(a1, rb1[0], acc, 0, 0, 0);
                const int ff = (t - 96) * 16 + lm;   // 0..47
                #pragma unroll
                for (int i = 0; i < 4; ++i)
                    fs[(quad * 4 + i) * 48 + ff] = acc[i];
            }
        }
        __syncthreads();                               // B2

        // ---------- Phase 3: softmax (exp2) + PV (MFMA) + ELU/mean ----------
        const int r = wid;
        short* attn_r = attn16 + r * NN * ATS;

        const int gg = lane >> 5;            // column group
        const int i  = lane & 31;            // e-row (active if < 24)
        const int jb = gg * 12;

        const float f1i = fs[r * 48 + i];
        const int mr = (i < NN) ? i : 0;

        float f2v[12], mrow[12];
        {
            const float* fp = fs + r * 48 + NN + jb;   // wave-uniform: bcast
            const float4 fa = *(const float4*)(fp);
            const float4 fb = *(const float4*)(fp + 4);
            const float4 fc = *(const float4*)(fp + 8);
            f2v[0]=fa.x; f2v[1]=fa.y; f2v[2]=fa.z; f2v[3]=fa.w;
            f2v[4]=fb.x; f2v[5]=fb.y; f2v[6]=fb.z; f2v[7]=fb.w;
            f2v[8]=fc.x; f2v[9]=fc.y; f2v[10]=fc.z; f2v[11]=fc.w;
            const float* mp = maskQ + gg * 288 + mr * 4;
            const float4 ma = *(const float4*)(mp);
            const float4 mb = *(const float4*)(mp + 96);
            const float4 mc = *(const float4*)(mp + 192);
            mrow[0]=ma.x; mrow[1]=ma.y; mrow[2]=ma.z; mrow[3]=ma.w;
            mrow[4]=mb.x; mrow[5]=mb.y; mrow[6]=mb.z; mrow[7]=mb.w;
            mrow[8]=mc.x; mrow[9]=mc.y; mrow[10]=mc.z; mrow[11]=mc.w;
        }

        float ev[12];
        float ssum = 0.f;
        #pragma unroll
        for (int j = 0; j < 12; ++j) {
            float e = f1i + f2v[j];
            e = fmaxf(e, ALPHA_ * e);                 // leaky relu
            const float p = exp2_fast(e + mrow[j]);   // masked: +(-9e15) -> 0
            ev[j] = p;
            ssum += p;
        }
        const float tot = ssum + __shfl_xor(ssum, 32, 64);
        const float inv = rcp_fast(tot);

        if (i < NN) {
            int pq[6];
            #pragma unroll
            for (int q = 0; q < 6; ++q)
                pq[q] = pk2bf(ev[2 * q] * inv, ev[2 * q + 1] * inv);
            short* dst = attn_r + i * ATS + jb;
            if (gg == 0) {     // cols 0..11: b128 @ +0, b64 @ +16B
                *(int4*)(dst)     = make_int4(pq[0], pq[1], pq[2], pq[3]);
                *(int2*)(dst + 8) = make_int2(pq[4], pq[5]);
            } else {           // cols 12..23: b64 @ +24B, b128 @ +32B
                *(int2*)(dst)     = make_int2(pq[0], pq[1]);
                *(int4*)(dst + 4) = make_int4(pq[2], pq[3], pq[4], pq[5]);
            }
        }
        // same-wave LDS write->read (in-order DS pipe; validated)

        // PV: attn (24x24) @ Wh (24x64), 2 M-tiles x 4 N-tiles MFMA.
        const short* pa0src = (quad < 3) ? (attn_r + lm * ATS + quad * 8) : zero16;
        const short* pa1src = (quad < 3 && lm < 8)
            ? (attn_r + (16 + lm) * ATS + quad * 8) : zero16;
        const bf16x8 pa0 = *(const bf16x8*)pa0src;
        const bf16x8 pa1 = *(const bf16x8*)pa1src;
        #pragma unroll
        for (int ntp = 0; ntp < 4; ++ntp) {
            const short* bsrc = (lane < 48)
                ? (whB + r * 1536 + (ntp * 48 + lane) * 8) : zero16;
            const bf16x8 bw = *(const bf16x8*)bsrc;
            f32x4 c0 = {0.f, 0.f, 0.f, 0.f};
            f32x4 c1 = {0.f, 0.f, 0.f, 0.f};
            __builtin_amdgcn_s_setprio(1);
            c0 = __builtin_amdgcn_mfma_f32_16x16x32_bf16(pa0, bw, c0, 0, 0, 0);
            c1 = __builtin_amdgcn_mfma_f32_16x16x32_bf16(pa1, bw, c1, 0, 0, 0);
            __builtin_amdgcn_s_setprio(0);
            float s = 0.f;
            #pragma unroll
            for (int k = 0; k < 4; ++k)
                s += elu_fast(c0[k]);
            #pragma unroll
            for (int k = 0; k < 4; ++k)
                s += elu_fast(c1[k]);
            s += __shfl_xor(s, 16, 64);
            s += __shfl_xor(s, 32, 64);
            if (quad == 0)
                out[(base + r) * HH + ntp * 16 + lm] = s * (1.0f / 24.0f);
        }
        __syncthreads();                               // B3 (buffer reuse)
    }
}

// ---------------------------------------------------------------------------
extern "C" void kernel_launch(void* const* d_in, const int* in_sizes, int n_in,
                              void* d_out, int out_size, void* d_ws, size_t ws_size,
                              hipStream_t stream)
{
    const float* x   = (const float*)d_in[0];
    const int*   adj = (const int*)d_in[1];
    const float* Wp  = (const float*)d_in[2];
    const float* bp  = (const float*)d_in[3];
    const float* W   = (const float*)d_in[4];
    const float* a   = (const float*)d_in[5];
    float* out = (float*)d_out;

    short* Bpk   = (short*)d_ws;                           // 99*1024 bf16
    float* bpWx  = (float*)(Bpk + (size_t)NTILE * 1024);   // 1584 fp32
    float* maskf = bpWx + CCX;                             // 576 fp32

    precompute_kernel<<<115, 256, 0, stream>>>(Wp, bp, W, a, adj, Bpk, bpWx, maskf);
    gat_main_kernel<<<BT_TOT / (ROWS * GRPS), 1024, 0, stream>>>(x, maskf, Bpk, bpWx, out);
}

// Round 8
// 117.990 us; speedup vs baseline: 1.0170x; 1.0170x over previous
//
#include <hip/hip_runtime.h>
#include <hip/hip_bf16.h>

#define F_IN   64
#define NN     24
#define HH     64
#define CC     1536           // Wh columns
#define CCX    1584           // + 48 f1/f2 columns
#define NTILE  99             // 1584 / 16 MFMA column tiles
#define ROWS   16             // BT rows per block (M=16 MFMA fully used)
#define BT_TOT (16 * 2048)    // 32768
#define ALPHA_ 0.2f
#define NEG_INF_ -9.0e15f
#define LOG2E_ 1.4426950408889634f
#define ATS    24             // attn16 row stride in shorts (48 B, 16B-aligned)

typedef short bf16x8 __attribute__((ext_vector_type(8)));
typedef float f32x4  __attribute__((ext_vector_type(4)));

#if defined(__has_builtin)
#  if __has_builtin(__builtin_amdgcn_cvt_pk_bf16_f32)
#    define HAS_PK_BF16 1
#  endif
#  if __has_builtin(__builtin_amdgcn_exp2f)
#    define HAS_EXP2 1
#  endif
#  if __has_builtin(__builtin_amdgcn_rcpf)
#    define HAS_RCP 1
#  endif
#  if __has_builtin(__builtin_amdgcn_fmed3f)
#    define HAS_MED3 1
#  endif
#endif
#ifndef HAS_PK_BF16
#  define HAS_PK_BF16 0
#endif
#ifndef HAS_EXP2
#  define HAS_EXP2 0
#endif
#ifndef HAS_RCP
#  define HAS_RCP 0
#endif
#ifndef HAS_MED3
#  define HAS_MED3 0
#endif

// fp32 -> bf16 bits, round-to-nearest-even
__device__ __forceinline__ short f2bf(float f) {
    unsigned u = __float_as_uint(f);
    return (short)((u + 0x7FFFu + ((u >> 16) & 1u)) >> 16);
}

// two fp32 -> packed bf16 pair in one int (low = a, high = b)
__device__ __forceinline__ int pk2bf(float a, float b) {
#if HAS_PK_BF16
    typedef __bf16 bfv2 __attribute__((ext_vector_type(2)));
    bfv2 r = __builtin_amdgcn_cvt_pk_bf16_f32(a, b);
    return __builtin_bit_cast(int, r);
#else
    return (int)(unsigned short)f2bf(a) | ((int)f2bf(b) << 16);
#endif
}

// 2^x, single v_exp_f32
__device__ __forceinline__ float exp2_fast(float x) {
#if HAS_EXP2
    return __builtin_amdgcn_exp2f(x);
#else
    return __expf(0.6931471805599453f * x);
#endif
}

// fast reciprocal (v_rcp_f32); ~1e-7 rel err, fine for bf16 attention weights
__device__ __forceinline__ float rcp_fast(float x) {
#if HAS_RCP
    return __builtin_amdgcn_rcpf(x);
#else
    return 1.0f / x;
#endif
}

// ELU(v) = median(v, e^v - 1, 0): v>0 -> med=v; v<=0 -> med=e^v-1. Inf-safe.
__device__ __forceinline__ float elu_fast(float v) {
#if HAS_MED3
    return __builtin_amdgcn_fmed3f(v, exp2_fast(v * LOG2E_) - 1.f, 0.f);
#else
    return (v > 0.f) ? v : (exp2_fast(v * LOG2E_) - 1.f);
#endif
}

// pack 8 fp32 -> bf16x8 via 4 cvt_pk
__device__ __forceinline__ bf16x8 pk8bf(float4 lo, float4 hi) {
    int4 r;
    r.x = pk2bf(lo.x, lo.y);
    r.y = pk2bf(lo.z, lo.w);
    r.z = pk2bf(hi.x, hi.y);
    r.w = pk2bf(hi.z, hi.w);
    return __builtin_bit_cast(bf16x8, r);
}

// ---------------------------------------------------------------------------
// Precompute: unchanged (verified r0-r5).
// ---------------------------------------------------------------------------
__global__ __launch_bounds__(256) void precompute_kernel(
    const float* __restrict__ Wp,
    const float* __restrict__ bp,
    const float* __restrict__ W,
    const float* __restrict__ a,
    const int*   __restrict__ adj,
    short* __restrict__ Bpk,
    float* __restrict__ bpWx,
    float* __restrict__ maskf)
{
    __shared__ float WpS[64 * 65];
    __shared__ float WS[64 * 17];
    __shared__ float Wa[128];
    const int b = blockIdx.x, tid = threadIdx.x;

    if (b < 96) {
        const int n64 = (b >> 2) * 64;
        const int jc0 = (b & 3) * 16;
        for (int i = tid; i < 4096; i += 256)
            WpS[(i >> 6) * 65 + (i & 63)] = Wp[(size_t)(i >> 6) * CC + n64 + (i & 63)];
        for (int i = tid; i < 1024; i += 256)
            WS[(i >> 4) * 17 + (i & 15)] = W[(i >> 4) * 64 + jc0 + (i & 15)];
        __syncthreads();

        const int k = tid & 63, q0 = (tid >> 6) * 4;
        float acc[4] = {0.f, 0.f, 0.f, 0.f};
        #pragma unroll 4
        for (int m = 0; m < 64; ++m) {
            const float wp = WpS[k * 65 + m];
            #pragma unroll
            for (int j = 0; j < 4; ++j)
                acc[j] += wp * WS[m * 17 + q0 + j];
        }
        const int s2 = k >> 5, jj = k & 7, lbase = ((k >> 3) & 3) * 16;
        #pragma unroll
        for (int j = 0; j < 4; ++j) {
            const int l = lbase + q0 + j;
            Bpk[((size_t)(b * 2 + s2) * 64 + l) * 8 + jj] = f2bf(acc[j]);
        }
    } else {
        const bool needWa = (b < 108) || (b == 114);
        if (needWa) {
            if (tid < 128) {
                const int which = tid >> 6, m = tid & 63;
                float s = 0.f;
                #pragma unroll 8
                for (int h = 0; h < 64; ++h)
                    s += W[m * 64 + h] * a[which * 64 + h];
                Wa[tid] = s;
            }
            __syncthreads();
        }
        if (b < 108) {
            const int u  = (b - 96) * 256 + tid;
            const int jj = u & 7, l = (u >> 3) & 63, s2 = (u >> 9) & 1, te = u >> 10;
            const int t  = 96 + te;
            const int k  = s2 * 32 + ((l >> 4) << 3) + jj;
            const int ff = te * 16 + (l & 15);
            const int which = (ff >= NN) ? 1 : 0;
            const int node  = ff - which * NN;
            float v = 0.f;
            #pragma unroll 8
            for (int m = 0; m < 64; ++m)
                v += Wp[(size_t)k * CC + node * 64 + m] * Wa[which * 64 + m];
            Bpk[((size_t)(t * 2 + s2) * 64 + l) * 8 + jj] = f2bf(v * LOG2E_);
        } else {
            const int c = (b - 108) * 256 + tid;
            if (c < CC) {
                const int n = c >> 6, jc = c & 63;
                float s = 0.f;
                #pragma unroll 8
                for (int m = 0; m < 64; ++m) s += bp[n * 64 + m] * W[m * 64 + jc];
                bpWx[c] = s;
            } else if (c < CCX) {
                const int ff = c - CC;
                const int which = (ff >= NN) ? 1 : 0;
                const int node  = ff - which * NN;
                float s = 0.f;
                #pragma unroll 8
                for (int m = 0; m < 64; ++m) s += bp[node * 64 + m] * Wa[which * 64 + m];
                bpWx[c] = s * LOG2E_;
            }
            if (b == 114) {                  // additive mask: 0 or NEG_INF
                for (int i = tid; i < NN * NN; i += 256)
                    maskf[i] = (adj[i] > 0) ? 0.f : NEG_INF_;
            }
        }
    }
}

// ---------------------------------------------------------------------------
// Main fused kernel, v8 = r4/r5 structure (2048 blocks, 2 blocks/CU) with
// the x LDS round-trip removed:
//   A-fragments load DIRECTLY from global (4 x float4 of row base+lm; all 16
//   waves share the same 4 KB -> L1/L2 broadcast) and pack via cvt_pk.
//   This deletes xs16, its ds_write/ds_read_b128 ops, and barrier B1 -- the
//   kernel now has a SINGLE __syncthreads (phase2 writes -> phase3 reads).
// Phase 2: int4 whB writes at the bank floor (conflict-free); bias as MFMA
//   C-init. Phase 3: exp2-domain softmax, two 24-lane groups x 12 cols;
//   quad-transposed mask; v_rcp; PV MFMA pair in setprio(1); ELU via med3.
// ---------------------------------------------------------------------------
__global__ __launch_bounds__(1024, 8) void gat_main_kernel(
    const float* __restrict__ x,
    const float* __restrict__ maskf,
    const short* __restrict__ Bpk,
    const float* __restrict__ bpWx,
    float* __restrict__ out)
{
    __shared__ __align__(16) short whB[ROWS * 4 * 48 * 8];    // 49152 B (PV B-frags)
    __shared__ __align__(16) short attn16[ROWS * NN * ATS];   // 18432 B (PV A, 24x24)
    __shared__ __align__(16) short zero16[8];                 //    16 B (zero bcast)
    __shared__ __align__(16) float maskQ[6 * 24 * 4];         //  2304 B (mask, q-transposed)
    __shared__ float fs[ROWS * 48];                           //  3072 B (f1|f2)

    const int tid  = threadIdx.x;
    const int lane = tid & 63;
    const int wid  = tid >> 6;           // 0..15
    const int quad = lane >> 4;
    const int lm   = lane & 15;
    const size_t base = (size_t)blockIdx.x * ROWS;

    // ---- A-fragments: direct global load of x row (base+lm), fp32 ----
    const float* xr = x + (base + lm) * F_IN + quad * 8;
    const float4 xa = *(const float4*)(xr);
    const float4 xb = *(const float4*)(xr + 4);
    const float4 xc = *(const float4*)(xr + 32);
    const float4 xd = *(const float4*)(xr + 36);

    if (tid < 8) zero16[tid] = 0;
    // mask staged transposed: element (i, j=g*12+q*4+c) -> maskQ[((g*3+q)*24+i)*4+c]
    if (tid < NN * NN) {
        const int i = tid / NN, rem = tid - i * NN;
        const int gg = (rem >= 12) ? 1 : 0;
        const int jl = rem - gg * 12;
        const int q = jl >> 2, c = jl & 3;
        maskQ[((gg * 3 + q) * NN + i) * 4 + c] = maskf[tid];
    }

    // ---------- Phase 2 (MFMA): [Wh | f1 | f2] = x_tile @ Bfused + bias ----
    {
        const bf16x8 a0 = pk8bf(xa, xb);
        const bf16x8 a1 = pk8bf(xc, xd);

        if (wid < 12) {
            // wave owns q-group g (nodes 8g..8g+7), n-tile nt (cols nt*16+lm)
            const int g  = wid >> 2;
            const int nt = wid & 3;
            short* wb0 = whB + ((nt * 48 + g * 16 + lm) * 8) + quad * 4 * 1536;
            int pA[4], pB[4];                       // half-0 packed pairs
            {   // ---- half 0: nodes 8g..8g+3 (jj 0..3) ----
                f32x4 acc[4];
                #pragma unroll
                for (int k = 0; k < 4; ++k) {
                    const int t = (g * 8 + k) * 4 + nt;
                    const short* bq = Bpk + ((size_t)(t * 2) * 64 + lane) * 8;
                    const bf16x8 b0 = *(const bf16x8*)bq;
                    const bf16x8 b1 = *(const bf16x8*)(bq + 512);
                    const float bb = bpWx[t * 16 + lm];   // bias as MFMA C-init
                    f32x4 c = {bb, bb, bb, bb};
                    c = __builtin_amdgcn_mfma_f32_16x16x32_bf16(a0, b0, c, 0, 0, 0);
                    c = __builtin_amdgcn_mfma_f32_16x16x32_bf16(a1, b1, c, 0, 0, 0);
                    acc[k] = c;
                }
                #pragma unroll
                for (int i = 0; i < 4; ++i) {
                    pA[i] = pk2bf(acc[0][i], acc[1][i]);
                    pB[i] = pk2bf(acc[2][i], acc[3][i]);
                }
            }
            {   // ---- half 1: nodes 8g+4..8g+7 (jj 4..7) + int4 store ----
                f32x4 acc[4];
                #pragma unroll
                for (int k = 0; k < 4; ++k) {
                    const int t = (g * 8 + 4 + k) * 4 + nt;
                    const short* bq = Bpk + ((size_t)(t * 2) * 64 + lane) * 8;
                    const bf16x8 b0 = *(const bf16x8*)bq;
                    const bf16x8 b1 = *(const bf16x8*)(bq + 512);
                    const float bb = bpWx[t * 16 + lm];
                    f32x4 c = {bb, bb, bb, bb};
                    c = __builtin_amdgcn_mfma_f32_16x16x32_bf16(a0, b0, c, 0, 0, 0);
                    c = __builtin_amdgcn_mfma_f32_16x16x32_bf16(a1, b1, c, 0, 0, 0);
                    acc[k] = c;
                }
                // C/D: col = lane&15, row = quad*4+reg. One 16-B write per
                // i-row: jj slots 0..7 = {pA, pB, half1 pairs} -> bank-exact.
                #pragma unroll
                for (int i = 0; i < 4; ++i) {
                    int4 w;
                    w.x = pA[i];
                    w.y = pB[i];
                    w.z = pk2bf(acc[0][i], acc[1][i]);
                    w.w = pk2bf(acc[2][i], acc[3][i]);
                    *(int4*)(wb0 + i * 1536) = w;
                }
            }
        } else if (wid < 15) {
            // f1/f2 tiles 96..98
            const int t = 96 + (wid - 12);
            const short* bq = Bpk + ((size_t)(t * 2) * 64 + lane) * 8;
            const bf16x8 b0 = *(const bf16x8*)bq;
            const bf16x8 b1 = *(const bf16x8*)(bq + 512);
            const float bb = bpWx[t * 16 + lm];
            f32x4 acc = {bb, bb, bb, bb};
            acc = __builtin_amdgcn_mfma_f32_16x16x32_bf16(a0, b0, acc, 0, 0, 0);
            acc = __builtin_amdgcn_mfma_f32_16x16x32_bf16(a1, b1, acc, 0, 0, 0);
            const int ff = (t - 96) * 16 + lm;   // 0..47
            #pragma unroll
            for (int i = 0; i < 4; ++i)
                fs[(quad * 4 + i) * 48 + ff] = acc[i];
        }
    }
    __syncthreads();          // single barrier: P2 writes -> P3 reads

    // ---------- Phase 3: softmax (exp2 domain) + PV (MFMA) + ELU/mean ------
    // wave wid handles exactly row r = wid; two 24-lane groups split the
    // 24 columns (gg=0: j 0..11, gg=1: j 12..23).
    const int r = wid;
    short* attn_r = attn16 + r * NN * ATS;

    const int gg = lane >> 5;            // column group
    const int i  = lane & 31;            // e-row (active if < 24)
    const int jb = gg * 12;

    const float f1i = fs[r * 48 + i];            // i<=31 < 48: in-bounds
    const int mr = (i < NN) ? i : 0;             // clamp for pad lanes

    float f2v[12], mrow[12];
    {
        const float* fp = fs + r * 48 + NN + jb; // wave-uniform per group: bcast
        const float4 fa = *(const float4*)(fp);
        const float4 fb = *(const float4*)(fp + 4);
        const float4 fc = *(const float4*)(fp + 8);
        f2v[0]=fa.x; f2v[1]=fa.y; f2v[2]=fa.z; f2v[3]=fa.w;
        f2v[4]=fb.x; f2v[5]=fb.y; f2v[6]=fb.z; f2v[7]=fb.w;
        f2v[8]=fc.x; f2v[9]=fc.y; f2v[10]=fc.z; f2v[11]=fc.w;
        // quad-transposed mask: each load = contiguous 16-B lane stride.
        const float* mp = maskQ + gg * 288 + mr * 4;
        const float4 ma = *(const float4*)(mp);
        const float4 mb = *(const float4*)(mp + 96);
        const float4 mc = *(const float4*)(mp + 192);
        mrow[0]=ma.x; mrow[1]=ma.y; mrow[2]=ma.z; mrow[3]=ma.w;
        mrow[4]=mb.x; mrow[5]=mb.y; mrow[6]=mb.z; mrow[7]=mb.w;
        mrow[8]=mc.x; mrow[9]=mc.y; mrow[10]=mc.z; mrow[11]=mc.w;
    }

    float ev[12];
    float ssum = 0.f;
    #pragma unroll
    for (int j = 0; j < 12; ++j) {
        float e = f1i + f2v[j];
        e = fmaxf(e, ALPHA_ * e);                 // leaky relu (alpha < 1)
        const float p = exp2_fast(e + mrow[j]);   // masked: +(-9e15) -> 0
        ev[j] = p;
        ssum += p;
    }
    const float tot = ssum + __shfl_xor(ssum, 32, 64);  // combine j-halves
    const float inv = rcp_fast(tot);

    if (i < NN) {
        int pq[6];
        #pragma unroll
        for (int q = 0; q < 6; ++q)
            pq[q] = pk2bf(ev[2 * q] * inv, ev[2 * q + 1] * inv);
        short* dst = attn_r + i * ATS + jb;
        if (gg == 0) {     // cols 0..11: b128 @ +0, b64 @ +16B
            *(int4*)(dst)     = make_int4(pq[0], pq[1], pq[2], pq[3]);
            *(int2*)(dst + 8) = make_int2(pq[4], pq[5]);
        } else {           // cols 12..23: b64 @ +24B, b128 @ +32B
            *(int2*)(dst)     = make_int2(pq[0], pq[1]);
            *(int4*)(dst + 4) = make_int4(pq[2], pq[3], pq[4], pq[5]);
        }
    }
    // same-wave LDS write->read (in-order DS pipe; validated r4-r11)

    // PV: attn (24x24) @ Wh (24x64), 2 M-tiles x 4 N-tiles MFMA.
    // Pads from register zero-selects:
    //   quad 3 (k=24..31) -> zero; tile-1 rows 24..31 (lm>=8) -> zero.
    const short* pa0src = (quad < 3) ? (attn_r + lm * ATS + quad * 8) : zero16;
    const short* pa1src = (quad < 3 && lm < 8)
        ? (attn_r + (16 + lm) * ATS + quad * 8) : zero16;
    const bf16x8 pa0 = *(const bf16x8*)pa0src;
    const bf16x8 pa1 = *(const bf16x8*)pa1src;
    #pragma unroll
    for (int ntp = 0; ntp < 4; ++ntp) {
        // lanes 48..63 hold the k=24..31 zero pad -> broadcast zero16
        const short* bsrc = (lane < 48)
            ? (whB + r * 1536 + (ntp * 48 + lane) * 8) : zero16;
        const bf16x8 bw = *(const bf16x8*)bsrc;
        f32x4 c0 = {0.f, 0.f, 0.f, 0.f};
        f32x4 c1 = {0.f, 0.f, 0.f, 0.f};
        __builtin_amdgcn_s_setprio(1);
        c0 = __builtin_amdgcn_mfma_f32_16x16x32_bf16(pa0, bw, c0, 0, 0, 0);
        c1 = __builtin_amdgcn_mfma_f32_16x16x32_bf16(pa1, bw, c1, 0, 0, 0);
        __builtin_amdgcn_s_setprio(0);
        // D: col = lane&15 = h_local, row = quad*4+reg = i; rows>=24 exact 0.
        float s = 0.f;
        #pragma unroll
        for (int k = 0; k < 4; ++k)
            s += elu_fast(c0[k]);
        #pragma unroll
        for (int k = 0; k < 4; ++k)
            s += elu_fast(c1[k]);
        s += __shfl_xor(s, 16, 64);
        s += __shfl_xor(s, 32, 64);
        if (quad == 0)
            out[(base + r) * HH + ntp * 16 + lm] = s * (1.0f / 24.0f);
    }
}

// ---------------------------------------------------------------------------
extern "C" void kernel_launch(void* const* d_in, const int* in_sizes, int n_in,
                              void* d_out, int out_size, void* d_ws, size_t ws_size,
                              hipStream_t stream)
{
    const float* x   = (const float*)d_in[0];
    const int*   adj = (const int*)d_in[1];
    const float* Wp  = (const float*)d_in[2];
    const float* bp  = (const float*)d_in[3];
    const float* W   = (const float*)d_in[4];
    const float* a   = (const float*)d_in[5];
    float* out = (float*)d_out;

    short* Bpk   = (short*)d_ws;                           // 99*1024 bf16
    float* bpWx  = (float*)(Bpk + (size_t)NTILE * 1024);   // 1584 fp32
    float* maskf = bpWx + CCX;                             // 576 fp32

    precompute_kernel<<<115, 256, 0, stream>>>(Wp, bp, W, a, adj, Bpk, bpWx, maskf);
    gat_main_kernel<<<BT_TOT / ROWS, 1024, 0, stream>>>(x, maskf, Bpk, bpWx, out);
}

// Round 9
// 108.033 us; speedup vs baseline: 1.1107x; 1.0922x over previous
//
#include <hip/hip_runtime.h>
#include <hip/hip_bf16.h>

#define F_IN   64
#define NN     24
#define HH     64
#define CC     1536           // Wh columns
#define CCX    1584           // + 48 f1/f2 columns
#define NTILE  99             // 1584 / 16 MFMA column tiles
#define ROWS   16             // BT rows per block (M=16 MFMA fully used)
#define BT_TOT (16 * 2048)    // 32768
#define ALPHA_ 0.2f
#define NEG_INF_ -9.0e15f
#define LOG2E_ 1.4426950408889634f
#define XSP    72             // xs16 row stride in shorts (144 B)
#define ATS    24             // attn16 row stride in shorts (48 B, 16B-aligned)

typedef short bf16x8 __attribute__((ext_vector_type(8)));
typedef float f32x4  __attribute__((ext_vector_type(4)));

#if defined(__has_builtin)
#  if __has_builtin(__builtin_amdgcn_cvt_pk_bf16_f32)
#    define HAS_PK_BF16 1
#  endif
#  if __has_builtin(__builtin_amdgcn_exp2f)
#    define HAS_EXP2 1
#  endif
#  if __has_builtin(__builtin_amdgcn_rcpf)
#    define HAS_RCP 1
#  endif
#  if __has_builtin(__builtin_amdgcn_fmed3f)
#    define HAS_MED3 1
#  endif
#endif
#ifndef HAS_PK_BF16
#  define HAS_PK_BF16 0
#endif
#ifndef HAS_EXP2
#  define HAS_EXP2 0
#endif
#ifndef HAS_RCP
#  define HAS_RCP 0
#endif
#ifndef HAS_MED3
#  define HAS_MED3 0
#endif

// fp32 -> bf16 bits, round-to-nearest-even
__device__ __forceinline__ short f2bf(float f) {
    unsigned u = __float_as_uint(f);
    return (short)((u + 0x7FFFu + ((u >> 16) & 1u)) >> 16);
}

// two fp32 -> packed bf16 pair in one int (low = a, high = b)
__device__ __forceinline__ int pk2bf(float a, float b) {
#if HAS_PK_BF16
    typedef __bf16 bfv2 __attribute__((ext_vector_type(2)));
    bfv2 r = __builtin_amdgcn_cvt_pk_bf16_f32(a, b);
    return __builtin_bit_cast(int, r);
#else
    return (int)(unsigned short)f2bf(a) | ((int)f2bf(b) << 16);
#endif
}

// 2^x, single v_exp_f32
__device__ __forceinline__ float exp2_fast(float x) {
#if HAS_EXP2
    return __builtin_amdgcn_exp2f(x);
#else
    return __expf(0.6931471805599453f * x);
#endif
}

// fast reciprocal (v_rcp_f32); ~1e-7 rel err, fine for bf16 attention weights
__device__ __forceinline__ float rcp_fast(float x) {
#if HAS_RCP
    return __builtin_amdgcn_rcpf(x);
#else
    return 1.0f / x;
#endif
}

// ELU(v) = median(v, e^v - 1, 0): v>0 -> med=v; v<=0 -> med=e^v-1. Inf-safe.
__device__ __forceinline__ float elu_fast(float v) {
#if HAS_MED3
    return __builtin_amdgcn_fmed3f(v, exp2_fast(v * LOG2E_) - 1.f, 0.f);
#else
    return (v > 0.f) ? v : (exp2_fast(v * LOG2E_) - 1.f);
#endif
}

// ---------------------------------------------------------------------------
// Precompute: LDS-staged, coalesced.
//  blocks 0..95   : main tile t=b (Wp/W slices staged in LDS).
//  blocks 96..107 : extra tiles t=96..98 (f1/f2 weights, pre-scaled by log2 e
//                   so the softmax runs in exp2 domain), Wa in LDS.
//  blocks 108..114: fused bias bpWx[1584] (f-part scaled by log2 e);
//                   block 114 also emits the additive mask, ALREADY in the
//                   quad-transposed layout the main kernel consumes:
//                   (i, j=gg*12+q*4+c) -> maskf[((gg*3+q)*24+i)*4+c].
// Packed layout: Bpk[((t*2+s)*64 + l)*8 + jj] = Bfused[k=s*32+(l>>4)*8+jj]
//                                                     [c=t*16+(l&15)]
// ---------------------------------------------------------------------------
__global__ __launch_bounds__(256) void precompute_kernel(
    const float* __restrict__ Wp,
    const float* __restrict__ bp,
    const float* __restrict__ W,
    const float* __restrict__ a,
    const int*   __restrict__ adj,
    short* __restrict__ Bpk,
    float* __restrict__ bpWx,
    float* __restrict__ maskf)
{
    __shared__ float WpS[64 * 65];
    __shared__ float WS[64 * 17];
    __shared__ float Wa[128];
    const int b = blockIdx.x, tid = threadIdx.x;

    if (b < 96) {
        const int n64 = (b >> 2) * 64;
        const int jc0 = (b & 3) * 16;
        for (int i = tid; i < 4096; i += 256)
            WpS[(i >> 6) * 65 + (i & 63)] = Wp[(size_t)(i >> 6) * CC + n64 + (i & 63)];
        for (int i = tid; i < 1024; i += 256)
            WS[(i >> 4) * 17 + (i & 15)] = W[(i >> 4) * 64 + jc0 + (i & 15)];
        __syncthreads();

        const int k = tid & 63, q0 = (tid >> 6) * 4;
        float acc[4] = {0.f, 0.f, 0.f, 0.f};
        #pragma unroll 4
        for (int m = 0; m < 64; ++m) {
            const float wp = WpS[k * 65 + m];
            #pragma unroll
            for (int j = 0; j < 4; ++j)
                acc[j] += wp * WS[m * 17 + q0 + j];
        }
        const int s2 = k >> 5, jj = k & 7, lbase = ((k >> 3) & 3) * 16;
        #pragma unroll
        for (int j = 0; j < 4; ++j) {
            const int l = lbase + q0 + j;
            Bpk[((size_t)(b * 2 + s2) * 64 + l) * 8 + jj] = f2bf(acc[j]);
        }
    } else {
        const bool needWa = (b < 108) || (b == 114);
        if (needWa) {
            if (tid < 128) {
                const int which = tid >> 6, m = tid & 63;
                float s = 0.f;
                #pragma unroll 8
                for (int h = 0; h < 64; ++h)
                    s += W[m * 64 + h] * a[which * 64 + h];
                Wa[tid] = s;
            }
            __syncthreads();
        }
        if (b < 108) {
            const int u  = (b - 96) * 256 + tid;
            const int jj = u & 7, l = (u >> 3) & 63, s2 = (u >> 9) & 1, te = u >> 10;
            const int t  = 96 + te;
            const int k  = s2 * 32 + ((l >> 4) << 3) + jj;
            const int ff = te * 16 + (l & 15);
            const int which = (ff >= NN) ? 1 : 0;
            const int node  = ff - which * NN;
            float v = 0.f;
            #pragma unroll 8
            for (int m = 0; m < 64; ++m)
                v += Wp[(size_t)k * CC + node * 64 + m] * Wa[which * 64 + m];
            Bpk[((size_t)(t * 2 + s2) * 64 + l) * 8 + jj] = f2bf(v * LOG2E_);
        } else {
            const int c = (b - 108) * 256 + tid;
            if (c < CC) {
                const int n = c >> 6, jc = c & 63;
                float s = 0.f;
                #pragma unroll 8
                for (int m = 0; m < 64; ++m) s += bp[n * 64 + m] * W[m * 64 + jc];
                bpWx[c] = s;
            } else if (c < CCX) {
                const int ff = c - CC;
                const int which = (ff >= NN) ? 1 : 0;
                const int node  = ff - which * NN;
                float s = 0.f;
                #pragma unroll 8
                for (int m = 0; m < 64; ++m) s += bp[node * 64 + m] * Wa[which * 64 + m];
                bpWx[c] = s * LOG2E_;
            }
            if (b == 114) {
                // additive mask, quad-transposed: (i,j) -> [((gg*3+q)*24+i)*4+c]
                for (int u = tid; u < NN * NN; u += 256) {
                    const int i = u / NN, j = u - i * NN;
                    const int gg = (j >= 12) ? 1 : 0;
                    const int jl = j - gg * 12;
                    const int q = jl >> 2, cc = jl & 3;
                    maskf[((gg * 3 + q) * NN + i) * 4 + cc] =
                        (adj[u] > 0) ? 0.f : NEG_INF_;
                }
            }
        }
    }
}

// ---------------------------------------------------------------------------
// Main fused kernel (r4-verified structure, consolidated):
// 2048 blocks x 1024 threads (16 waves), 2 blocks/CU = 32 waves/CU (max).
// Phase 2: waves 0..11 each own one (q-group g, n-tile nt) pair and compute
//   all 8 nodes of that group. Half-0's packed bf16 pairs are buffered in
//   registers; after half 1 each i-row is written as ONE int4 (16 B) ->
//   lane addr = quad*12288B + lm*16B: all 32 banks, 8 accesses each at
//   distinct addresses = exact bank-cycle floor (conflict-free). Waves
//   12..14 compute the f1/f2 tiles.
// Phase 3: softmax in exp2 domain, two 24-lane groups per wave (gg=lane>>5)
//   each handle 12 columns; f2 read from LDS (wave-uniform broadcast);
//   mask staged as a straight copy (pre-transposed in precompute) and read
//   at contiguous 16-B lane stride (conflict-free); v_rcp for 1/sum;
//   ELU via v_med3.
// ---------------------------------------------------------------------------
__global__ __launch_bounds__(1024, 8) void gat_main_kernel(
    const float* __restrict__ x,
    const float* __restrict__ maskf,
    const short* __restrict__ Bpk,
    const float* __restrict__ bpWx,
    float* __restrict__ out)
{
    __shared__ __align__(16) short xs16[ROWS * XSP];          //  2304 B
    __shared__ __align__(16) short whB[ROWS * 4 * 48 * 8];    // 49152 B (PV B-frags)
    __shared__ __align__(16) short attn16[ROWS * NN * ATS];   // 18432 B (PV A, 24x24)
    __shared__ __align__(16) short zero16[8];                 //    16 B (zero bcast)
    __shared__ __align__(16) float maskQ[6 * 24 * 4];         //  2304 B (mask, q-transposed)
    __shared__ float fs[ROWS * 48];                           //  3072 B (f1|f2)

    const int tid  = threadIdx.x;
    const int lane = tid & 63;
    const int wid  = tid >> 6;           // 0..15
    const int quad = lane >> 4;
    const int lm   = lane & 15;
    const size_t base = (size_t)blockIdx.x * ROWS;

    if (tid < 8) zero16[tid] = 0;
    if (tid < NN * NN) maskQ[tid] = maskf[tid];   // pre-transposed: straight copy
    // stage x rows as bf16 (A-operand): 1024 elements, 1 per thread.
    {
        const int rr = tid >> 6, k = tid & 63;
        xs16[rr * XSP + k] = f2bf(x[base * F_IN + tid]);
    }
    __syncthreads();

    // ---------- Phase 2 (MFMA): [Wh | f1 | f2] = x_tile @ Bfused + bias ----
    {
        const bf16x8 a0 = *(const bf16x8*)(xs16 + lm * XSP + quad * 8);
        const bf16x8 a1 = *(const bf16x8*)(xs16 + lm * XSP + 32 + quad * 8);

        if (wid < 12) {
            // wave owns q-group g (nodes 8g..8g+7), n-tile nt (cols nt*16+lm)
            const int g  = wid >> 2;
            const int nt = wid & 3;
            short* wb0 = whB + ((nt * 48 + g * 16 + lm) * 8) + quad * 4 * 1536;
            int pA[4], pB[4];                       // half-0 packed pairs
            {   // ---- half 0: nodes 8g..8g+3 (jj 0..3) ----
                f32x4 acc[4];
                #pragma unroll
                for (int k = 0; k < 4; ++k) {
                    const int t = (g * 8 + k) * 4 + nt;
                    const short* bq = Bpk + ((size_t)(t * 2) * 64 + lane) * 8;
                    const bf16x8 b0 = *(const bf16x8*)bq;
                    const bf16x8 b1 = *(const bf16x8*)(bq + 512);
                    const float bb = bpWx[t * 16 + lm];   // bias as MFMA C-init
                    f32x4 c = {bb, bb, bb, bb};
                    c = __builtin_amdgcn_mfma_f32_16x16x32_bf16(a0, b0, c, 0, 0, 0);
                    c = __builtin_amdgcn_mfma_f32_16x16x32_bf16(a1, b1, c, 0, 0, 0);
                    acc[k] = c;
                }
                #pragma unroll
                for (int i = 0; i < 4; ++i) {
                    pA[i] = pk2bf(acc[0][i], acc[1][i]);
                    pB[i] = pk2bf(acc[2][i], acc[3][i]);
                }
            }
            {   // ---- half 1: nodes 8g+4..8g+7 (jj 4..7) + int4 store ----
                f32x4 acc[4];
                #pragma unroll
                for (int k = 0; k < 4; ++k) {
                    const int t = (g * 8 + 4 + k) * 4 + nt;
                    const short* bq = Bpk + ((size_t)(t * 2) * 64 + lane) * 8;
                    const bf16x8 b0 = *(const bf16x8*)bq;
                    const bf16x8 b1 = *(const bf16x8*)(bq + 512);
                    const float bb = bpWx[t * 16 + lm];
                    f32x4 c = {bb, bb, bb, bb};
                    c = __builtin_amdgcn_mfma_f32_16x16x32_bf16(a0, b0, c, 0, 0, 0);
                    c = __builtin_amdgcn_mfma_f32_16x16x32_bf16(a1, b1, c, 0, 0, 0);
                    acc[k] = c;
                }
                // C/D: col = lane&15, row = quad*4+reg. One 16-B write per
                // i-row: jj slots 0..7 = {pA, pB, half1 pairs} -> bank-exact.
                #pragma unroll
                for (int i = 0; i < 4; ++i) {
                    int4 w;
                    w.x = pA[i];
                    w.y = pB[i];
                    w.z = pk2bf(acc[0][i], acc[1][i]);
                    w.w = pk2bf(acc[2][i], acc[3][i]);
                    *(int4*)(wb0 + i * 1536) = w;
                }
            }
        } else if (wid < 15) {
            // f1/f2 tiles 96..98
            const int t = 96 + (wid - 12);
            const short* bq = Bpk + ((size_t)(t * 2) * 64 + lane) * 8;
            const bf16x8 b0 = *(const bf16x8*)bq;
            const bf16x8 b1 = *(const bf16x8*)(bq + 512);
            const float bb = bpWx[t * 16 + lm];
            f32x4 acc = {bb, bb, bb, bb};
            acc = __builtin_amdgcn_mfma_f32_16x16x32_bf16(a0, b0, acc, 0, 0, 0);
            acc = __builtin_amdgcn_mfma_f32_16x16x32_bf16(a1, b1, acc, 0, 0, 0);
            const int ff = (t - 96) * 16 + lm;   // 0..47
            #pragma unroll
            for (int i = 0; i < 4; ++i)
                fs[(quad * 4 + i) * 48 + ff] = acc[i];
        }
    }
    __syncthreads();

    // ---------- Phase 3: softmax (exp2 domain) + PV (MFMA) + ELU/mean ------
    // wave wid handles exactly row r = wid; two 24-lane groups split the
    // 24 columns (gg=0: j 0..11, gg=1: j 12..23).
    const int r = wid;
    short* attn_r = attn16 + r * NN * ATS;

    const int gg = lane >> 5;            // column group
    const int i  = lane & 31;            // e-row (active if < 24)
    const int jb = gg * 12;

    const float f1i = fs[r * 48 + i];            // i<=31 < 48: in-bounds
    const int mr = (i < NN) ? i : 0;             // clamp for pad lanes

    float f2v[12], mrow[12];
    {
        const float* fp = fs + r * 48 + NN + jb; // wave-uniform per group: bcast
        const float4 fa = *(const float4*)(fp);
        const float4 fb = *(const float4*)(fp + 4);
        const float4 fc = *(const float4*)(fp + 8);
        f2v[0]=fa.x; f2v[1]=fa.y; f2v[2]=fa.z; f2v[3]=fa.w;
        f2v[4]=fb.x; f2v[5]=fb.y; f2v[6]=fb.z; f2v[7]=fb.w;
        f2v[8]=fc.x; f2v[9]=fc.y; f2v[10]=fc.z; f2v[11]=fc.w;
        // quad-transposed mask: each load = contiguous 16-B lane stride.
        const float* mp = maskQ + gg * 288 + mr * 4;
        const float4 ma = *(const float4*)(mp);
        const float4 mb = *(const float4*)(mp + 96);
        const float4 mc = *(const float4*)(mp + 192);
        mrow[0]=ma.x; mrow[1]=ma.y; mrow[2]=ma.z; mrow[3]=ma.w;
        mrow[4]=mb.x; mrow[5]=mb.y; mrow[6]=mb.z; mrow[7]=mb.w;
        mrow[8]=mc.x; mrow[9]=mc.y; mrow[10]=mc.z; mrow[11]=mc.w;
    }

    float ev[12];
    float ssum = 0.f;
    #pragma unroll
    for (int j = 0; j < 12; ++j) {
        float e = f1i + f2v[j];
        e = fmaxf(e, ALPHA_ * e);                 // leaky relu (alpha < 1)
        const float p = exp2_fast(e + mrow[j]);   // masked: +(-9e15) -> 0
        ev[j] = p;
        ssum += p;
    }
    const float tot = ssum + __shfl_xor(ssum, 32, 64);  // combine j-halves
    const float inv = rcp_fast(tot);

    if (i < NN) {
        int pq[6];
        #pragma unroll
        for (int q = 0; q < 6; ++q)
            pq[q] = pk2bf(ev[2 * q] * inv, ev[2 * q + 1] * inv);
        short* dst = attn_r + i * ATS + jb;
        if (gg == 0) {     // cols 0..11: b128 @ +0, b64 @ +16B
            *(int4*)(dst)     = make_int4(pq[0], pq[1], pq[2], pq[3]);
            *(int2*)(dst + 8) = make_int2(pq[4], pq[5]);
        } else {           // cols 12..23: b64 @ +24B, b128 @ +32B
            *(int2*)(dst)     = make_int2(pq[0], pq[1]);
            *(int4*)(dst + 4) = make_int4(pq[2], pq[3], pq[4], pq[5]);
        }
    }
    // same-wave LDS write->read (in-order DS pipe; validated r4-r11)

    // PV: attn (24x24) @ Wh (24x64), 2 M-tiles x 4 N-tiles MFMA.
    // Pads from register zero-selects:
    //   quad 3 (k=24..31) -> zero; tile-1 rows 24..31 (lm>=8) -> zero.
    const short* pa0src = (quad < 3) ? (attn_r + lm * ATS + quad * 8) : zero16;
    const short* pa1src = (quad < 3 && lm < 8)
        ? (attn_r + (16 + lm) * ATS + quad * 8) : zero16;
    const bf16x8 pa0 = *(const bf16x8*)pa0src;
    const bf16x8 pa1 = *(const bf16x8*)pa1src;
    #pragma unroll
    for (int ntp = 0; ntp < 4; ++ntp) {
        // lanes 48..63 hold the k=24..31 zero pad -> broadcast zero16
        const short* bsrc = (lane < 48)
            ? (whB + r * 1536 + (ntp * 48 + lane) * 8) : zero16;
        const bf16x8 bw = *(const bf16x8*)bsrc;
        f32x4 c0 = {0.f, 0.f, 0.f, 0.f};
        f32x4 c1 = {0.f, 0.f, 0.f, 0.f};
        c0 = __builtin_amdgcn_mfma_f32_16x16x32_bf16(pa0, bw, c0, 0, 0, 0);
        c1 = __builtin_amdgcn_mfma_f32_16x16x32_bf16(pa1, bw, c1, 0, 0, 0);
        // D: col = lane&15 = h_local, row = quad*4+reg = i; rows>=24 exact 0.
        float s = 0.f;
        #pragma unroll
        for (int k = 0; k < 4; ++k)
            s += elu_fast(c0[k]);
        #pragma unroll
        for (int k = 0; k < 4; ++k)
            s += elu_fast(c1[k]);
        s += __shfl_xor(s, 16, 64);
        s += __shfl_xor(s, 32, 64);
        if (quad == 0)
            out[(base + r) * HH + ntp * 16 + lm] = s * (1.0f / 24.0f);
    }
}

// ---------------------------------------------------------------------------
extern "C" void kernel_launch(void* const* d_in, const int* in_sizes, int n_in,
                              void* d_out, int out_size, void* d_ws, size_t ws_size,
                              hipStream_t stream)
{
    const float* x   = (const float*)d_in[0];
    const int*   adj = (const int*)d_in[1];
    const float* Wp  = (const float*)d_in[2];
    const float* bp  = (const float*)d_in[3];
    const float* W   = (const float*)d_in[4];
    const float* a   = (const float*)d_in[5];
    float* out = (float*)d_out;

    short* Bpk   = (short*)d_ws;                           // 99*1024 bf16
    float* bpWx  = (float*)(Bpk + (size_t)NTILE * 1024);   // 1584 fp32
    float* maskf = bpWx + CCX;                             // 576 fp32

    precompute_kernel<<<115, 256, 0, stream>>>(Wp, bp, W, a, adj, Bpk, bpWx, maskf);
    gat_main_kernel<<<BT_TOT / ROWS, 1024, 0, stream>>>(x, maskf, Bpk, bpWx, out);
}

// Round 10
// 107.906 us; speedup vs baseline: 1.1120x; 1.0012x over previous
//
#include <hip/hip_runtime.h>
#include <hip/hip_bf16.h>

#define F_IN   64
#define NN     24
#define HH     64
#define CC     1536           // Wh columns
#define CCX    1584           // + 48 f1/f2 columns
#define NTILE  99             // 1584 / 16 MFMA column tiles
#define ROWS   16             // BT rows per block (M=16 MFMA fully used)
#define BT_TOT (16 * 2048)    // 32768
#define ALPHA_ 0.2f
#define NEG_INF_ -9.0e15f
#define LOG2E_ 1.4426950408889634f
#define XSP    72             // xs16 row stride in shorts (144 B)
#define ATS    24             // attn16 row stride in shorts (48 B, 16B-aligned)

typedef short bf16x8 __attribute__((ext_vector_type(8)));
typedef float f32x4  __attribute__((ext_vector_type(4)));

#if defined(__has_builtin)
#  if __has_builtin(__builtin_amdgcn_cvt_pk_bf16_f32)
#    define HAS_PK_BF16 1
#  endif
#  if __has_builtin(__builtin_amdgcn_exp2f)
#    define HAS_EXP2 1
#  endif
#  if __has_builtin(__builtin_amdgcn_rcpf)
#    define HAS_RCP 1
#  endif
#  if __has_builtin(__builtin_amdgcn_fmed3f)
#    define HAS_MED3 1
#  endif
#endif
#ifndef HAS_PK_BF16
#  define HAS_PK_BF16 0
#endif
#ifndef HAS_EXP2
#  define HAS_EXP2 0
#endif
#ifndef HAS_RCP
#  define HAS_RCP 0
#endif
#ifndef HAS_MED3
#  define HAS_MED3 0
#endif

// fp32 -> bf16 bits, round-to-nearest-even
__device__ __forceinline__ short f2bf(float f) {
    unsigned u = __float_as_uint(f);
    return (short)((u + 0x7FFFu + ((u >> 16) & 1u)) >> 16);
}

// two fp32 -> packed bf16 pair in one int (low = a, high = b)
__device__ __forceinline__ int pk2bf(float a, float b) {
#if HAS_PK_BF16
    typedef __bf16 bfv2 __attribute__((ext_vector_type(2)));
    bfv2 r = __builtin_amdgcn_cvt_pk_bf16_f32(a, b);
    return __builtin_bit_cast(int, r);
#else
    return (int)(unsigned short)f2bf(a) | ((int)f2bf(b) << 16);
#endif
}

// 2^x, single v_exp_f32
__device__ __forceinline__ float exp2_fast(float x) {
#if HAS_EXP2
    return __builtin_amdgcn_exp2f(x);
#else
    return __expf(0.6931471805599453f * x);
#endif
}

// fast reciprocal (v_rcp_f32); ~1e-7 rel err, fine for bf16 attention weights
__device__ __forceinline__ float rcp_fast(float x) {
#if HAS_RCP
    return __builtin_amdgcn_rcpf(x);
#else
    return 1.0f / x;
#endif
}

// ELU(v) = median(v, e^v - 1, 0): v>0 -> med=v; v<=0 -> med=e^v-1. Inf-safe.
__device__ __forceinline__ float elu_fast(float v) {
#if HAS_MED3
    return __builtin_amdgcn_fmed3f(v, exp2_fast(v * LOG2E_) - 1.f, 0.f);
#else
    return (v > 0.f) ? v : (exp2_fast(v * LOG2E_) - 1.f);
#endif
}

// ---------------------------------------------------------------------------
// Precompute: LDS-staged, coalesced.
//  blocks 0..95   : main tile t=b (Wp/W slices staged in LDS).
//  blocks 96..107 : extra tiles t=96..98 (f1/f2 weights, pre-scaled by log2 e
//                   so the softmax runs in exp2 domain), Wa in LDS.
//  blocks 108..114: fused bias bpWx[1584] (f-part scaled by log2 e);
//                   block 114 also emits the additive mask, ALREADY in the
//                   quad-transposed layout the main kernel consumes:
//                   (i, j=gg*12+q*4+c) -> maskf[((gg*3+q)*24+i)*4+c].
// Packed layout: Bpk[((t*2+s)*64 + l)*8 + jj] = Bfused[k=s*32+(l>>4)*8+jj]
//                                                     [c=t*16+(l&15)]
// ---------------------------------------------------------------------------
__global__ __launch_bounds__(256) void precompute_kernel(
    const float* __restrict__ Wp,
    const float* __restrict__ bp,
    const float* __restrict__ W,
    const float* __restrict__ a,
    const int*   __restrict__ adj,
    short* __restrict__ Bpk,
    float* __restrict__ bpWx,
    float* __restrict__ maskf)
{
    __shared__ float WpS[64 * 65];
    __shared__ float WS[64 * 17];
    __shared__ float Wa[128];
    const int b = blockIdx.x, tid = threadIdx.x;

    if (b < 96) {
        const int n64 = (b >> 2) * 64;
        const int jc0 = (b & 3) * 16;
        for (int i = tid; i < 4096; i += 256)
            WpS[(i >> 6) * 65 + (i & 63)] = Wp[(size_t)(i >> 6) * CC + n64 + (i & 63)];
        for (int i = tid; i < 1024; i += 256)
            WS[(i >> 4) * 17 + (i & 15)] = W[(i >> 4) * 64 + jc0 + (i & 15)];
        __syncthreads();

        const int k = tid & 63, q0 = (tid >> 6) * 4;
        float acc[4] = {0.f, 0.f, 0.f, 0.f};
        #pragma unroll 4
        for (int m = 0; m < 64; ++m) {
            const float wp = WpS[k * 65 + m];
            #pragma unroll
            for (int j = 0; j < 4; ++j)
                acc[j] += wp * WS[m * 17 + q0 + j];
        }
        const int s2 = k >> 5, jj = k & 7, lbase = ((k >> 3) & 3) * 16;
        #pragma unroll
        for (int j = 0; j < 4; ++j) {
            const int l = lbase + q0 + j;
            Bpk[((size_t)(b * 2 + s2) * 64 + l) * 8 + jj] = f2bf(acc[j]);
        }
    } else {
        const bool needWa = (b < 108) || (b == 114);
        if (needWa) {
            if (tid < 128) {
                const int which = tid >> 6, m = tid & 63;
                float s = 0.f;
                #pragma unroll 8
                for (int h = 0; h < 64; ++h)
                    s += W[m * 64 + h] * a[which * 64 + h];
                Wa[tid] = s;
            }
            __syncthreads();
        }
        if (b < 108) {
            const int u  = (b - 96) * 256 + tid;
            const int jj = u & 7, l = (u >> 3) & 63, s2 = (u >> 9) & 1, te = u >> 10;
            const int t  = 96 + te;
            const int k  = s2 * 32 + ((l >> 4) << 3) + jj;
            const int ff = te * 16 + (l & 15);
            const int which = (ff >= NN) ? 1 : 0;
            const int node  = ff - which * NN;
            float v = 0.f;
            #pragma unroll 8
            for (int m = 0; m < 64; ++m)
                v += Wp[(size_t)k * CC + node * 64 + m] * Wa[which * 64 + m];
            Bpk[((size_t)(t * 2 + s2) * 64 + l) * 8 + jj] = f2bf(v * LOG2E_);
        } else {
            const int c = (b - 108) * 256 + tid;
            if (c < CC) {
                const int n = c >> 6, jc = c & 63;
                float s = 0.f;
                #pragma unroll 8
                for (int m = 0; m < 64; ++m) s += bp[n * 64 + m] * W[m * 64 + jc];
                bpWx[c] = s;
            } else if (c < CCX) {
                const int ff = c - CC;
                const int which = (ff >= NN) ? 1 : 0;
                const int node  = ff - which * NN;
                float s = 0.f;
                #pragma unroll 8
                for (int m = 0; m < 64; ++m) s += bp[node * 64 + m] * Wa[which * 64 + m];
                bpWx[c] = s * LOG2E_;
            }
            if (b == 114) {
                // additive mask, quad-transposed: (i,j) -> [((gg*3+q)*24+i)*4+c]
                for (int u = tid; u < NN * NN; u += 256) {
                    const int i = u / NN, j = u - i * NN;
                    const int gg = (j >= 12) ? 1 : 0;
                    const int jl = j - gg * 12;
                    const int q = jl >> 2, cc = jl & 3;
                    maskf[((gg * 3 + q) * NN + i) * 4 + cc] =
                        (adj[u] > 0) ? 0.f : NEG_INF_;
                }
            }
        }
    }
}

// ---------------------------------------------------------------------------
// Main fused kernel (r9-verified structure + deferred softmax normalization):
// 2048 blocks x 1024 threads (16 waves), 2 blocks/CU = 32 waves/CU (max).
// Phase 2: waves 0..11 each own one (q-group g, n-tile nt) pair and compute
//   all 8 nodes of that group; one int4 (16 B) whB write per i-row at the
//   bank-cycle floor (conflict-free). Waves 12..14 compute the f1/f2 tiles.
// Phase 3: softmax in exp2 domain, two 24-lane groups per wave; RAW ev
//   stored to attn16 (rcp off the critical path); per-e-row 1/sum stashed
//   in invS and folded into the PV epilogue as elu(c * inv). invS tail
//   (rows 24..31 at r=15) zeroed so 0-pad x junk cannot produce NaN.
// ---------------------------------------------------------------------------
__global__ __launch_bounds__(1024, 8) void gat_main_kernel(
    const float* __restrict__ x,
    const float* __restrict__ maskf,
    const short* __restrict__ Bpk,
    const float* __restrict__ bpWx,
    float* __restrict__ out)
{
    __shared__ __align__(16) short xs16[ROWS * XSP];          //  2304 B
    __shared__ __align__(16) short whB[ROWS * 4 * 48 * 8];    // 49152 B (PV B-frags)
    __shared__ __align__(16) short attn16[ROWS * NN * ATS];   // 18432 B (PV A, raw ev)
    __shared__ __align__(16) short zero16[8];                 //    16 B (zero bcast)
    __shared__ __align__(16) float maskQ[6 * 24 * 4];         //  2304 B (mask, q-transposed)
    __shared__ __align__(16) float invS[ROWS * NN + 8];       //  1568 B (1/sum + pad)
    __shared__ float fs[ROWS * 48];                           //  3072 B (f1|f2)

    const int tid  = threadIdx.x;
    const int lane = tid & 63;
    const int wid  = tid >> 6;           // 0..15
    const int quad = lane >> 4;
    const int lm   = lane & 15;
    const size_t base = (size_t)blockIdx.x * ROWS;

    if (tid < 8) {
        zero16[tid] = 0;
        invS[ROWS * NN + tid] = 0.f;     // finite pad for r=15 tail reads
    }
    if (tid < NN * NN) maskQ[tid] = maskf[tid];   // pre-transposed: straight copy
    // stage x rows as bf16 (A-operand): 1024 elements, 1 per thread.
    {
        const int rr = tid >> 6, k = tid & 63;
        xs16[rr * XSP + k] = f2bf(x[base * F_IN + tid]);
    }
    __syncthreads();

    // ---------- Phase 2 (MFMA): [Wh | f1 | f2] = x_tile @ Bfused + bias ----
    {
        const bf16x8 a0 = *(const bf16x8*)(xs16 + lm * XSP + quad * 8);
        const bf16x8 a1 = *(const bf16x8*)(xs16 + lm * XSP + 32 + quad * 8);

        if (wid < 12) {
            // wave owns q-group g (nodes 8g..8g+7), n-tile nt (cols nt*16+lm)
            const int g  = wid >> 2;
            const int nt = wid & 3;
            short* wb0 = whB + ((nt * 48 + g * 16 + lm) * 8) + quad * 4 * 1536;
            int pA[4], pB[4];                       // half-0 packed pairs
            {   // ---- half 0: nodes 8g..8g+3 (jj 0..3) ----
                f32x4 acc[4];
                #pragma unroll
                for (int k = 0; k < 4; ++k) {
                    const int t = (g * 8 + k) * 4 + nt;
                    const short* bq = Bpk + ((size_t)(t * 2) * 64 + lane) * 8;
                    const bf16x8 b0 = *(const bf16x8*)bq;
                    const bf16x8 b1 = *(const bf16x8*)(bq + 512);
                    const float bb = bpWx[t * 16 + lm];   // bias as MFMA C-init
                    f32x4 c = {bb, bb, bb, bb};
                    c = __builtin_amdgcn_mfma_f32_16x16x32_bf16(a0, b0, c, 0, 0, 0);
                    c = __builtin_amdgcn_mfma_f32_16x16x32_bf16(a1, b1, c, 0, 0, 0);
                    acc[k] = c;
                }
                #pragma unroll
                for (int i = 0; i < 4; ++i) {
                    pA[i] = pk2bf(acc[0][i], acc[1][i]);
                    pB[i] = pk2bf(acc[2][i], acc[3][i]);
                }
            }
            {   // ---- half 1: nodes 8g+4..8g+7 (jj 4..7) + int4 store ----
                f32x4 acc[4];
                #pragma unroll
                for (int k = 0; k < 4; ++k) {
                    const int t = (g * 8 + 4 + k) * 4 + nt;
                    const short* bq = Bpk + ((size_t)(t * 2) * 64 + lane) * 8;
                    const bf16x8 b0 = *(const bf16x8*)bq;
                    const bf16x8 b1 = *(const bf16x8*)(bq + 512);
                    const float bb = bpWx[t * 16 + lm];
                    f32x4 c = {bb, bb, bb, bb};
                    c = __builtin_amdgcn_mfma_f32_16x16x32_bf16(a0, b0, c, 0, 0, 0);
                    c = __builtin_amdgcn_mfma_f32_16x16x32_bf16(a1, b1, c, 0, 0, 0);
                    acc[k] = c;
                }
                // C/D: col = lane&15, row = quad*4+reg. One 16-B write per
                // i-row: jj slots 0..7 = {pA, pB, half1 pairs} -> bank-exact.
                #pragma unroll
                for (int i = 0; i < 4; ++i) {
                    int4 w;
                    w.x = pA[i];
                    w.y = pB[i];
                    w.z = pk2bf(acc[0][i], acc[1][i]);
                    w.w = pk2bf(acc[2][i], acc[3][i]);
                    *(int4*)(wb0 + i * 1536) = w;
                }
            }
        } else if (wid < 15) {
            // f1/f2 tiles 96..98
            const int t = 96 + (wid - 12);
            const short* bq = Bpk + ((size_t)(t * 2) * 64 + lane) * 8;
            const bf16x8 b0 = *(const bf16x8*)bq;
            const bf16x8 b1 = *(const bf16x8*)(bq + 512);
            const float bb = bpWx[t * 16 + lm];
            f32x4 acc = {bb, bb, bb, bb};
            acc = __builtin_amdgcn_mfma_f32_16x16x32_bf16(a0, b0, acc, 0, 0, 0);
            acc = __builtin_amdgcn_mfma_f32_16x16x32_bf16(a1, b1, acc, 0, 0, 0);
            const int ff = (t - 96) * 16 + lm;   // 0..47
            #pragma unroll
            for (int i = 0; i < 4; ++i)
                fs[(quad * 4 + i) * 48 + ff] = acc[i];
        }
    }
    __syncthreads();

    // ---------- Phase 3: softmax (exp2 domain) + PV (MFMA) + ELU/mean ------
    // wave wid handles exactly row r = wid; two 24-lane groups split the
    // 24 columns (gg=0: j 0..11, gg=1: j 12..23).
    const int r = wid;
    short* attn_r = attn16 + r * NN * ATS;

    const int gg = lane >> 5;            // column group
    const int i  = lane & 31;            // e-row (active if < 24)
    const int jb = gg * 12;

    const float f1i = fs[r * 48 + i];            // i<=31 < 48: in-bounds
    const int mr = (i < NN) ? i : 0;             // clamp for pad lanes

    float f2v[12], mrow[12];
    {
        const float* fp = fs + r * 48 + NN + jb; // wave-uniform per group: bcast
        const float4 fa = *(const float4*)(fp);
        const float4 fb = *(const float4*)(fp + 4);
        const float4 fc = *(const float4*)(fp + 8);
        f2v[0]=fa.x; f2v[1]=fa.y; f2v[2]=fa.z; f2v[3]=fa.w;
        f2v[4]=fb.x; f2v[5]=fb.y; f2v[6]=fb.z; f2v[7]=fb.w;
        f2v[8]=fc.x; f2v[9]=fc.y; f2v[10]=fc.z; f2v[11]=fc.w;
        // quad-transposed mask: each load = contiguous 16-B lane stride.
        const float* mp = maskQ + gg * 288 + mr * 4;
        const float4 ma = *(const float4*)(mp);
        const float4 mb = *(const float4*)(mp + 96);
        const float4 mc = *(const float4*)(mp + 192);
        mrow[0]=ma.x; mrow[1]=ma.y; mrow[2]=ma.z; mrow[3]=ma.w;
        mrow[4]=mb.x; mrow[5]=mb.y; mrow[6]=mb.z; mrow[7]=mb.w;
        mrow[8]=mc.x; mrow[9]=mc.y; mrow[10]=mc.z; mrow[11]=mc.w;
    }

    float ev[12];
    float ssum = 0.f;
    #pragma unroll
    for (int j = 0; j < 12; ++j) {
        float e = f1i + f2v[j];
        e = fmaxf(e, ALPHA_ * e);                 // leaky relu (alpha < 1)
        const float p = exp2_fast(e + mrow[j]);   // masked: +(-9e15) -> 0
        ev[j] = p;
        ssum += p;
    }

    // pack RAW ev immediately (rcp + normalization deferred past PV MFMA)
    if (i < NN) {
        int pq[6];
        #pragma unroll
        for (int q = 0; q < 6; ++q)
            pq[q] = pk2bf(ev[2 * q], ev[2 * q + 1]);
        short* dst = attn_r + i * ATS + jb;
        if (gg == 0) {     // cols 0..11: b128 @ +0, b64 @ +16B
            *(int4*)(dst)     = make_int4(pq[0], pq[1], pq[2], pq[3]);
            *(int2*)(dst + 8) = make_int2(pq[4], pq[5]);
        } else {           // cols 12..23: b64 @ +24B, b128 @ +32B
            *(int2*)(dst)     = make_int2(pq[0], pq[1]);
            *(int4*)(dst + 4) = make_int4(pq[2], pq[3], pq[4], pq[5]);
        }
    }
    const float tot = ssum + __shfl_xor(ssum, 32, 64);  // combine j-halves
    if (gg == 0 && i < NN)
        invS[r * NN + i] = rcp_fast(tot);
    // same-wave LDS write->read (in-order DS pipe; validated r4-r11)

    // PV: raw-ev attn (24x24) @ Wh (24x64); normalization folded into ELU.
    // Pads from register zero-selects:
    //   quad 3 (k=24..31) -> zero; tile-1 rows 24..31 (lm>=8) -> zero.
    const short* pa0src = (quad < 3) ? (attn_r + lm * ATS + quad * 8) : zero16;
    const short* pa1src = (quad < 3 && lm < 8)
        ? (attn_r + (16 + lm) * ATS + quad * 8) : zero16;
    const bf16x8 pa0 = *(const bf16x8*)pa0src;
    const bf16x8 pa1 = *(const bf16x8*)pa1src;

    // per-row 1/sum for this lane's output rows (broadcast within quad).
    // c0 rows quad*4+k (always <16); c1 rows 16+quad*4+k (24..31 -> finite
    // junk x exact-0 pad = 0, tail zero-initialized for r=15).
    float iv0[4], iv1[4];
    {
        const float4 v0 = *(const float4*)(invS + r * NN + quad * 4);
        const float4 v1 = *(const float4*)(invS + r * NN + 16 + quad * 4);
        iv0[0]=v0.x; iv0[1]=v0.y; iv0[2]=v0.z; iv0[3]=v0.w;
        iv1[0]=v1.x; iv1[1]=v1.y; iv1[2]=v1.z; iv1[3]=v1.w;
    }

    #pragma unroll
    for (int ntp = 0; ntp < 4; ++ntp) {
        // lanes 48..63 hold the k=24..31 zero pad -> broadcast zero16
        const short* bsrc = (lane < 48)
            ? (whB + r * 1536 + (ntp * 48 + lane) * 8) : zero16;
        const bf16x8 bw = *(const bf16x8*)bsrc;
        f32x4 c0 = {0.f, 0.f, 0.f, 0.f};
        f32x4 c1 = {0.f, 0.f, 0.f, 0.f};
        c0 = __builtin_amdgcn_mfma_f32_16x16x32_bf16(pa0, bw, c0, 0, 0, 0);
        c1 = __builtin_amdgcn_mfma_f32_16x16x32_bf16(pa1, bw, c1, 0, 0, 0);
        // D: col = lane&15 = h_local, row = quad*4+reg = i; rows>=24 exact 0.
        float s = 0.f;
        #pragma unroll
        for (int k = 0; k < 4; ++k)
            s += elu_fast(c0[k] * iv0[k]);
        #pragma unroll
        for (int k = 0; k < 4; ++k)
            s += elu_fast(c1[k] * iv1[k]);
        s += __shfl_xor(s, 16, 64);
        s += __shfl_xor(s, 32, 64);
        if (quad == 0)
            out[(base + r) * HH + ntp * 16 + lm] = s * (1.0f / 24.0f);
    }
}

// ---------------------------------------------------------------------------
extern "C" void kernel_launch(void* const* d_in, const int* in_sizes, int n_in,
                              void* d_out, int out_size, void* d_ws, size_t ws_size,
                              hipStream_t stream)
{
    const float* x   = (const float*)d_in[0];
    const int*   adj = (const int*)d_in[1];
    const float* Wp  = (const float*)d_in[2];
    const float* bp  = (const float*)d_in[3];
    const float* W   = (const float*)d_in[4];
    const float* a   = (const float*)d_in[5];
    float* out = (float*)d_out;

    short* Bpk   = (short*)d_ws;                           // 99*1024 bf16
    float* bpWx  = (float*)(Bpk + (size_t)NTILE * 1024);   // 1584 fp32
    float* maskf = bpWx + CCX;                             // 576 fp32

    precompute_kernel<<<115, 256, 0, stream>>>(Wp, bp, W, a, adj, Bpk, bpWx, maskf);
    gat_main_kernel<<<BT_TOT / ROWS, 1024, 0, stream>>>(x, maskf, Bpk, bpWx, out);
}